// Round 8
// baseline (198.550 us; speedup 1.0000x reference)
//
#include <hip/hip_runtime.h>
#include <hip/hip_bf16.h>

#define BN 16
#define TN 2048
#define DN 64
#define EN 512
#define PAD 72   // Pt bf16 row stride (144 B)

using f32x4  = __attribute__((ext_vector_type(4))) float;
using bf16x8 = __attribute__((ext_vector_type(8))) short;
using bf16x4 = __attribute__((ext_vector_type(4))) short;

static __device__ __forceinline__ short f2bf(float f) {
    __hip_bfloat16 h = __float2bfloat16(f);
    return __builtin_bit_cast(short, h);
}
static __device__ __forceinline__ float bf2f(short s) {
    return __bfloat162float(__builtin_bit_cast(__hip_bfloat16, s));
}
// bijective XCD swizzle for nwg % 8 == 0: consecutive swizzled ids stay on one XCD
static __device__ __forceinline__ int xcd_swz(int bid, int nwg) {
    return (bid & 7) * (nwg >> 3) + (bid >> 3);
}

// ---------------------------------------------------------------------------
// Kernel W: split W^T into bf16 hi + lo. Unchanged.
// ---------------------------------------------------------------------------
__global__ __launch_bounds__(256) void wprep_kernel(
    const float* __restrict__ Wq, short* __restrict__ WTh,
    short* __restrict__ WTl)
{
    __shared__ float wlds[64][65];
    const int tid = threadIdx.x;
    const int k0 = blockIdx.x * 64;
    #pragma unroll
    for (int it = 0; it < 16; ++it) {
        int idx = it * 256 + tid;
        int k = idx >> 6, n = idx & 63;
        wlds[k][n] = Wq[(size_t)(k0 + k) * 64 + n];
    }
    __syncthreads();
    #pragma unroll
    for (int it = 0; it < 16; ++it) {
        int idx = it * 256 + tid;
        int n = idx >> 6, k = idx & 63;
        float v = wlds[k][n];
        short h = f2bf(v);
        short l = f2bf(v - bf2f(h));
        WTh[(size_t)n * EN + k0 + k] = h;
        WTl[(size_t)n * EN + k0 + k] = l;
    }
}

// ---------------------------------------------------------------------------
// Kernel A: Q = x @ W + bq via MFMA (bf16 hi+lo W, f32 accum). Unchanged (R6).
// ---------------------------------------------------------------------------
__global__ __launch_bounds__(256, 2) void qproj_kernel(
    const float* __restrict__ x, const short* __restrict__ WTh,
    const short* __restrict__ WTl, const float* __restrict__ bq,
    short* __restrict__ Qb, short* __restrict__ QTb)
{
    __shared__ short xh[64 * 40];
    __shared__ short wth[64 * 40];
    __shared__ short wtl[64 * 40];
    __shared__ short tl[64][68];

    const int tid = threadIdx.x;
    const int lane = tid & 63;
    const int wv = tid >> 6;
    const int c = lane & 15;
    const int g = lane >> 4;
    const int rowbase = blockIdx.x * 64;
    const int b = rowbase >> 11;
    const int tbase = rowbase & (TN - 1);

    const int sr = tid >> 3;
    const int sc4 = tid & 7;

    float4 xa = *reinterpret_cast<const float4*>(&x[(size_t)(rowbase + sr) * EN + sc4 * 4]);
    float4 xb = *reinterpret_cast<const float4*>(&x[(size_t)(rowbase + 32 + sr) * EN + sc4 * 4]);
    bf16x4 wa = *reinterpret_cast<const bf16x4*>(&WTh[(size_t)sr * EN + sc4 * 4]);
    bf16x4 wb = *reinterpret_cast<const bf16x4*>(&WTh[(size_t)(32 + sr) * EN + sc4 * 4]);
    bf16x4 la = *reinterpret_cast<const bf16x4*>(&WTl[(size_t)sr * EN + sc4 * 4]);
    bf16x4 lb = *reinterpret_cast<const bf16x4*>(&WTl[(size_t)(32 + sr) * EN + sc4 * 4]);

    f32x4 acc[4];
    #pragma unroll
    for (int nt = 0; nt < 4; ++nt) acc[nt] = (f32x4){0.f, 0.f, 0.f, 0.f};

    for (int ks = 0; ks < EN; ks += 32) {
        __syncthreads();
        bf16x4 h0, h1;
        #pragma unroll
        for (int j = 0; j < 4; ++j) { h0[j] = f2bf(xa[j]); h1[j] = f2bf(xb[j]); }
        *reinterpret_cast<bf16x4*>(&xh[sr * 40 + sc4 * 4]) = h0;
        *reinterpret_cast<bf16x4*>(&xh[(32 + sr) * 40 + sc4 * 4]) = h1;
        *reinterpret_cast<bf16x4*>(&wth[sr * 40 + sc4 * 4]) = wa;
        *reinterpret_cast<bf16x4*>(&wth[(32 + sr) * 40 + sc4 * 4]) = wb;
        *reinterpret_cast<bf16x4*>(&wtl[sr * 40 + sc4 * 4]) = la;
        *reinterpret_cast<bf16x4*>(&wtl[(32 + sr) * 40 + sc4 * 4]) = lb;

        const int kn = (ks + 32 < EN) ? ks + 32 : ks;
        xa = *reinterpret_cast<const float4*>(&x[(size_t)(rowbase + sr) * EN + kn + sc4 * 4]);
        xb = *reinterpret_cast<const float4*>(&x[(size_t)(rowbase + 32 + sr) * EN + kn + sc4 * 4]);
        wa = *reinterpret_cast<const bf16x4*>(&WTh[(size_t)sr * EN + kn + sc4 * 4]);
        wb = *reinterpret_cast<const bf16x4*>(&WTh[(size_t)(32 + sr) * EN + kn + sc4 * 4]);
        la = *reinterpret_cast<const bf16x4*>(&WTl[(size_t)sr * EN + kn + sc4 * 4]);
        lb = *reinterpret_cast<const bf16x4*>(&WTl[(size_t)(32 + sr) * EN + kn + sc4 * 4]);
        __syncthreads();

        bf16x8 av = *reinterpret_cast<const bf16x8*>(&xh[(wv * 16 + c) * 40 + g * 8]);
        #pragma unroll
        for (int nt = 0; nt < 4; ++nt) {
            bf16x8 bh = *reinterpret_cast<const bf16x8*>(&wth[(nt * 16 + c) * 40 + g * 8]);
            bf16x8 bl = *reinterpret_cast<const bf16x8*>(&wtl[(nt * 16 + c) * 40 + g * 8]);
            acc[nt] = __builtin_amdgcn_mfma_f32_16x16x32_bf16(av, bh, acc[nt], 0, 0, 0);
            acc[nt] = __builtin_amdgcn_mfma_f32_16x16x32_bf16(av, bl, acc[nt], 0, 0, 0);
        }
    }

    __syncthreads();
    #pragma unroll
    for (int nt = 0; nt < 4; ++nt) {
        const float bias = bq[nt * 16 + c];
        #pragma unroll
        for (int r = 0; r < 4; ++r) {
            const int row = wv * 16 + g * 4 + r;
            short qb = f2bf(acc[nt][r] + bias);
            Qb[(size_t)(rowbase + row) * DN + nt * 16 + c] = qb;
            tl[nt * 16 + c][row] = qb;
        }
    }
    __syncthreads();
    #pragma unroll
    for (int it = 0; it < 4; ++it) {
        int idx = it * 256 + tid;
        int d = idx >> 4;
        int j4 = (idx & 15) * 4;
        *reinterpret_cast<short4*>(&QTb[((size_t)(b * 64 + d)) * TN + tbase + j4]) =
            *reinterpret_cast<const short4*>(&tl[d][j4]);
    }
}

// ---------------------------------------------------------------------------
// Kernel B (v6): column-softmax inverse denominators. 1 wave per block, 16
// j-rows per wave, full i-stream direct from global (L1/L2-hot). Zero LDS,
// zero barriers -> pure streaming, waves fully independent.
// ---------------------------------------------------------------------------
__global__ __launch_bounds__(64, 2) void stats_kernel(
    const short* __restrict__ Qb, float* __restrict__ linv)
{
    const int bid = xcd_swz(blockIdx.x, (TN / 16) * BN);
    const int b = bid >> 7;                  // /128
    const int jbase = (bid & 127) * 16;
    const int lane = threadIdx.x;
    const int c = lane & 15;
    const int g = lane >> 4;
    const short* Qbb = Qb + (size_t)b * TN * DN;

    bf16x8 a0 = *reinterpret_cast<const bf16x8*>(Qbb + (size_t)(jbase + c) * DN + g * 8);
    bf16x8 a1 = *reinterpret_cast<const bf16x8*>(Qbb + (size_t)(jbase + c) * DN + g * 8 + 32);

    float l[4] = {0.f, 0.f, 0.f, 0.f};
    for (int ib = 0; ib < TN; ib += 64) {
        #pragma unroll
        for (int t = 0; t < 4; ++t) {
            const short* p = Qbb + (size_t)(ib + t * 16 + c) * DN + g * 8;
            bf16x8 b0 = *reinterpret_cast<const bf16x8*>(p);
            bf16x8 b1 = *reinterpret_cast<const bf16x8*>(p + 32);
            f32x4 acc = {0.f, 0.f, 0.f, 0.f};
            acc = __builtin_amdgcn_mfma_f32_16x16x32_bf16(a0, b0, acc, 0, 0, 0);
            acc = __builtin_amdgcn_mfma_f32_16x16x32_bf16(a1, b1, acc, 0, 0, 0);
            #pragma unroll
            for (int r = 0; r < 4; ++r)
                l[r] += __expf(acc[r] * 0.125f);
        }
    }
    #pragma unroll
    for (int r = 0; r < 4; ++r) {
        float v = l[r];
        v += __shfl_xor(v, 1);
        v += __shfl_xor(v, 2);
        v += __shfl_xor(v, 4);
        v += __shfl_xor(v, 8);
        l[r] = v;
    }
    if (c == 0) {
        #pragma unroll
        for (int r = 0; r < 4; ++r)
            linv[(size_t)b * TN + jbase + g * 4 + r] = 1.0f / l[r];
    }
}

// ---------------------------------------------------------------------------
// Kernel F: RT[b][d][j] = linv[b][j] * QT[b][d][j] (fold softmax denominator
// into the V-operand once).
// ---------------------------------------------------------------------------
__global__ __launch_bounds__(256) void fuse_kernel(
    const short* __restrict__ QTb, const float* __restrict__ linv,
    short* __restrict__ RT)
{
    const int idx = blockIdx.x * 256 + threadIdx.x;   // 0..262143
    const int c8 = idx & 255;
    const int bd = idx >> 8;
    const int b = bd >> 6;
    const int j0 = c8 * 8;

    bf16x8 q = *reinterpret_cast<const bf16x8*>(&QTb[(size_t)bd * TN + j0]);
    const float* lp = linv + (size_t)b * TN + j0;
    bf16x8 r;
    #pragma unroll
    for (int t = 0; t < 8; ++t)
        r[t] = f2bf(bf2f(q[t]) * lp[t]);
    *reinterpret_cast<bf16x8*>(&RT[(size_t)bd * TN + j0]) = r;
}

// ---------------------------------------------------------------------------
// Kernel C (v6): out[i,:] = sum_j exp(S[i,j]/8) * RT[:,j]
// 1 wave per block, 16 i per wave, full j-loop (32 iters of 64 j). All MFMA
// fragments direct from global (L1/L2-hot); A-frags double-buffered in regs
// (next-iter loads issued BEFORE the Pt fence). Only LDS use: wave-private
// Pt round-trip (D-layout b64 write -> exact B-frag b128 read). Zero
// __syncthreads. Direct f32x4 stores (no atomics).
// ---------------------------------------------------------------------------
__global__ __launch_bounds__(64, 2) void pv_kernel(
    const short* __restrict__ Qb, const short* __restrict__ RT,
    float* __restrict__ out)
{
    __shared__ short Pt[16 * PAD];        // 2.3 KB, wave-private
    const int bid = xcd_swz(blockIdx.x, (TN / 16) * BN);
    const int b = bid >> 7;
    const int ibase = (bid & 127) * 16;
    const int lane = threadIdx.x;
    const int c = lane & 15;
    const int g = lane >> 4;
    const short* Qbb = Qb + (size_t)b * TN * DN;
    const short* RTb = RT + (size_t)b * DN * TN;

    // invariant MFMA1 B-frags (i-rows)
    bf16x8 bi0 = *reinterpret_cast<const bf16x8*>(Qbb + (size_t)(ibase + c) * DN + g * 8);
    bf16x8 bi1 = *reinterpret_cast<const bf16x8*>(Qbb + (size_t)(ibase + c) * DN + g * 8 + 32);

    f32x4 o[4];
    #pragma unroll
    for (int dt = 0; dt < 4; ++dt) o[dt] = (f32x4){0.f, 0.f, 0.f, 0.f};

    // prefetch A-frags for jb=0 (j-rows jt*16+c)
    bf16x8 curA[4][2];
    #pragma unroll
    for (int jt = 0; jt < 4; ++jt) {
        const short* p = Qbb + (size_t)(jt * 16 + c) * DN + g * 8;
        curA[jt][0] = *reinterpret_cast<const bf16x8*>(p);
        curA[jt][1] = *reinterpret_cast<const bf16x8*>(p + 32);
    }

    for (int jb = 0; jb < TN; jb += 64) {
        // --- phase A: MFMA1 S^T tiles -> P = exp(s/8) -> Pt (b64 writes) ---
        #pragma unroll
        for (int jt = 0; jt < 4; ++jt) {
            f32x4 accs = {0.f, 0.f, 0.f, 0.f};
            accs = __builtin_amdgcn_mfma_f32_16x16x32_bf16(curA[jt][0], bi0, accs, 0, 0, 0);
            accs = __builtin_amdgcn_mfma_f32_16x16x32_bf16(curA[jt][1], bi1, accs, 0, 0, 0);
            bf16x4 pw;
            #pragma unroll
            for (int r = 0; r < 4; ++r)
                pw[r] = f2bf(__expf(accs[r] * 0.125f));
            *reinterpret_cast<bf16x4*>(&Pt[c * PAD + jt * 16 + g * 4]) = pw;
        }

        // issue next-iter A loads + this-iter RT loads BEFORE the LDS fence
        const int jn = (jb + 64 < TN) ? jb + 64 : jb;
        bf16x8 nxtA[4][2];
        #pragma unroll
        for (int jt = 0; jt < 4; ++jt) {
            const short* p = Qbb + (size_t)(jn + jt * 16 + c) * DN + g * 8;
            nxtA[jt][0] = *reinterpret_cast<const bf16x8*>(p);
            nxtA[jt][1] = *reinterpret_cast<const bf16x8*>(p + 32);
        }
        bf16x8 rr[4][2];
        #pragma unroll
        for (int dt = 0; dt < 4; ++dt) {
            const short* p = RTb + (size_t)(dt * 16 + c) * TN + jb + g * 8;
            rr[dt][0] = *reinterpret_cast<const bf16x8*>(p);
            rr[dt][1] = *reinterpret_cast<const bf16x8*>(p + 32);
        }

        // wave-private Pt RAW ordering (LDS only; global loads use vmcnt)
        asm volatile("s_waitcnt lgkmcnt(0)" ::: "memory");
        __builtin_amdgcn_sched_barrier(0);

        // --- phase B: MFMA2 outT[d][i] += RT[d][j] * P[j][i] ---
        bf16x8 p0 = *reinterpret_cast<const bf16x8*>(&Pt[c * PAD + g * 8]);
        bf16x8 p1 = *reinterpret_cast<const bf16x8*>(&Pt[c * PAD + 32 + g * 8]);
        #pragma unroll
        for (int dt = 0; dt < 4; ++dt) {
            o[dt] = __builtin_amdgcn_mfma_f32_16x16x32_bf16(rr[dt][0], p0, o[dt], 0, 0, 0);
            o[dt] = __builtin_amdgcn_mfma_f32_16x16x32_bf16(rr[dt][1], p1, o[dt], 0, 0, 0);
        }

        #pragma unroll
        for (int jt = 0; jt < 4; ++jt) {
            curA[jt][0] = nxtA[jt][0];
            curA[jt][1] = nxtA[jt][1];
        }
    }

    // epilogue: lane holds outT[dt*16+g*4+r][ibase+c] -> float4 stores
    float* outb = out + (size_t)b * TN * DN;
    #pragma unroll
    for (int dt = 0; dt < 4; ++dt) {
        float4 v4;
        v4.x = o[dt][0]; v4.y = o[dt][1]; v4.z = o[dt][2]; v4.w = o[dt][3];
        *reinterpret_cast<float4*>(&outb[(size_t)(ibase + c) * DN + dt * 16 + g * 4]) = v4;
    }
}

extern "C" void kernel_launch(void* const* d_in, const int* in_sizes, int n_in,
                              void* d_out, int out_size, void* d_ws, size_t ws_size,
                              hipStream_t stream) {
    const float* x  = (const float*)d_in[0];
    const float* Wq = (const float*)d_in[1];
    const float* bq = (const float*)d_in[2];
    float* out = (float*)d_out;

    short* Qb   = (short*)d_ws;                           // 4 MB
    short* QTb  = Qb + (size_t)BN * TN * DN;              // 4 MB
    short* RT   = QTb + (size_t)BN * TN * DN;             // 4 MB
    float* linv = (float*)(RT + (size_t)BN * TN * DN);    // 128 KB
    short* WTh  = (short*)(linv + (size_t)BN * TN);       // 64 KB
    short* WTl  = WTh + (size_t)DN * EN;                  // 64 KB

    wprep_kernel<<<dim3(EN / 64), dim3(256), 0, stream>>>(Wq, WTh, WTl);
    qproj_kernel<<<dim3(BN * TN / 64), dim3(256), 0, stream>>>(x, WTh, WTl, bq, Qb, QTb);
    stats_kernel<<<dim3((TN / 16) * BN), dim3(64), 0, stream>>>(Qb, linv);
    fuse_kernel<<<dim3(BN * DN * TN / 8 / 256), dim3(256), 0, stream>>>(QTb, linv, RT);
    pv_kernel<<<dim3((TN / 16) * BN), dim3(64), 0, stream>>>(Qb, RT, out);
}

// Round 9
// 82.493 us; speedup vs baseline: 2.4069x; 2.4069x over previous
//
#include <hip/hip_runtime.h>
#include <hip/hip_bf16.h>

#define BN 16
#define TN 2048
#define DN 64
#define EN 512
#define PAD 68   // bf16 row stride 136B: conflict-free for both our DS patterns

using f32x4  = __attribute__((ext_vector_type(4))) float;
using bf16x8 = __attribute__((ext_vector_type(8))) short;
using bf16x4 = __attribute__((ext_vector_type(4))) short;

static __device__ __forceinline__ short f2bf(float f) {
    __hip_bfloat16 h = __float2bfloat16(f);
    return __builtin_bit_cast(short, h);
}
static __device__ __forceinline__ float bf2f(short s) {
    return __bfloat162float(__builtin_bit_cast(__hip_bfloat16, s));
}

// ---------------------------------------------------------------------------
// Kernel W: split W^T into bf16 hi + lo. Unchanged.
// ---------------------------------------------------------------------------
__global__ __launch_bounds__(256) void wprep_kernel(
    const float* __restrict__ Wq, short* __restrict__ WTh,
    short* __restrict__ WTl)
{
    __shared__ float wlds[64][65];
    const int tid = threadIdx.x;
    const int k0 = blockIdx.x * 64;
    #pragma unroll
    for (int it = 0; it < 16; ++it) {
        int idx = it * 256 + tid;
        int k = idx >> 6, n = idx & 63;
        wlds[k][n] = Wq[(size_t)(k0 + k) * 64 + n];
    }
    __syncthreads();
    #pragma unroll
    for (int it = 0; it < 16; ++it) {
        int idx = it * 256 + tid;
        int n = idx >> 6, k = idx & 63;
        float v = wlds[k][n];
        short h = f2bf(v);
        short l = f2bf(v - bf2f(h));
        WTh[(size_t)n * EN + k0 + k] = h;
        WTl[(size_t)n * EN + k0 + k] = l;
    }
}

// ---------------------------------------------------------------------------
// Kernel A: Q = x @ W + bq via MFMA (bf16 hi+lo W, f32 accum). Unchanged (R6).
// ---------------------------------------------------------------------------
__global__ __launch_bounds__(256, 2) void qproj_kernel(
    const float* __restrict__ x, const short* __restrict__ WTh,
    const short* __restrict__ WTl, const float* __restrict__ bq,
    short* __restrict__ Qb, short* __restrict__ QTb)
{
    __shared__ short xh[64 * 40];
    __shared__ short wth[64 * 40];
    __shared__ short wtl[64 * 40];
    __shared__ short tl[64][68];

    const int tid = threadIdx.x;
    const int lane = tid & 63;
    const int wv = tid >> 6;
    const int c = lane & 15;
    const int g = lane >> 4;
    const int rowbase = blockIdx.x * 64;
    const int b = rowbase >> 11;
    const int tbase = rowbase & (TN - 1);

    const int sr = tid >> 3;
    const int sc4 = tid & 7;

    float4 xa = *reinterpret_cast<const float4*>(&x[(size_t)(rowbase + sr) * EN + sc4 * 4]);
    float4 xb = *reinterpret_cast<const float4*>(&x[(size_t)(rowbase + 32 + sr) * EN + sc4 * 4]);
    bf16x4 wa = *reinterpret_cast<const bf16x4*>(&WTh[(size_t)sr * EN + sc4 * 4]);
    bf16x4 wb = *reinterpret_cast<const bf16x4*>(&WTh[(size_t)(32 + sr) * EN + sc4 * 4]);
    bf16x4 la = *reinterpret_cast<const bf16x4*>(&WTl[(size_t)sr * EN + sc4 * 4]);
    bf16x4 lb = *reinterpret_cast<const bf16x4*>(&WTl[(size_t)(32 + sr) * EN + sc4 * 4]);

    f32x4 acc[4];
    #pragma unroll
    for (int nt = 0; nt < 4; ++nt) acc[nt] = (f32x4){0.f, 0.f, 0.f, 0.f};

    for (int ks = 0; ks < EN; ks += 32) {
        __syncthreads();
        bf16x4 h0, h1;
        #pragma unroll
        for (int j = 0; j < 4; ++j) { h0[j] = f2bf(xa[j]); h1[j] = f2bf(xb[j]); }
        *reinterpret_cast<bf16x4*>(&xh[sr * 40 + sc4 * 4]) = h0;
        *reinterpret_cast<bf16x4*>(&xh[(32 + sr) * 40 + sc4 * 4]) = h1;
        *reinterpret_cast<bf16x4*>(&wth[sr * 40 + sc4 * 4]) = wa;
        *reinterpret_cast<bf16x4*>(&wth[(32 + sr) * 40 + sc4 * 4]) = wb;
        *reinterpret_cast<bf16x4*>(&wtl[sr * 40 + sc4 * 4]) = la;
        *reinterpret_cast<bf16x4*>(&wtl[(32 + sr) * 40 + sc4 * 4]) = lb;

        const int kn = (ks + 32 < EN) ? ks + 32 : ks;
        xa = *reinterpret_cast<const float4*>(&x[(size_t)(rowbase + sr) * EN + kn + sc4 * 4]);
        xb = *reinterpret_cast<const float4*>(&x[(size_t)(rowbase + 32 + sr) * EN + kn + sc4 * 4]);
        wa = *reinterpret_cast<const bf16x4*>(&WTh[(size_t)sr * EN + kn + sc4 * 4]);
        wb = *reinterpret_cast<const bf16x4*>(&WTh[(size_t)(32 + sr) * EN + kn + sc4 * 4]);
        la = *reinterpret_cast<const bf16x4*>(&WTl[(size_t)sr * EN + kn + sc4 * 4]);
        lb = *reinterpret_cast<const bf16x4*>(&WTl[(size_t)(32 + sr) * EN + kn + sc4 * 4]);
        __syncthreads();

        bf16x8 av = *reinterpret_cast<const bf16x8*>(&xh[(wv * 16 + c) * 40 + g * 8]);
        #pragma unroll
        for (int nt = 0; nt < 4; ++nt) {
            bf16x8 bh = *reinterpret_cast<const bf16x8*>(&wth[(nt * 16 + c) * 40 + g * 8]);
            bf16x8 bl = *reinterpret_cast<const bf16x8*>(&wtl[(nt * 16 + c) * 40 + g * 8]);
            acc[nt] = __builtin_amdgcn_mfma_f32_16x16x32_bf16(av, bh, acc[nt], 0, 0, 0);
            acc[nt] = __builtin_amdgcn_mfma_f32_16x16x32_bf16(av, bl, acc[nt], 0, 0, 0);
        }
    }

    __syncthreads();
    #pragma unroll
    for (int nt = 0; nt < 4; ++nt) {
        const float bias = bq[nt * 16 + c];
        #pragma unroll
        for (int r = 0; r < 4; ++r) {
            const int row = wv * 16 + g * 4 + r;
            short qb = f2bf(acc[nt][r] + bias);
            Qb[(size_t)(rowbase + row) * DN + nt * 16 + c] = qb;
            tl[nt * 16 + c][row] = qb;
        }
    }
    __syncthreads();
    #pragma unroll
    for (int it = 0; it < 4; ++it) {
        int idx = it * 256 + tid;
        int d = idx >> 4;
        int j4 = (idx & 15) * 4;
        *reinterpret_cast<short4*>(&QTb[((size_t)(b * 64 + d)) * TN + tbase + j4]) =
            *reinterpret_cast<const short4*>(&tl[d][j4]);
    }
}

// ---------------------------------------------------------------------------
// Kernel B: partial column-softmax sums (z halves the i-range). Grid
// (TN/64, BN, 2); partial row-sums to l_part[z][b][t]; no atomics. (R7 form,
// PAD=68.)
// ---------------------------------------------------------------------------
__global__ __launch_bounds__(256, 4) void stats_kernel(
    const short* __restrict__ Qb, float* __restrict__ l_part)
{
    __shared__ short Qt[64 * PAD];
    const int tid = threadIdx.x;
    const int lane = tid & 63;
    const int wv = tid >> 6;
    const int c = lane & 15;
    const int g = lane >> 4;
    const int b = blockIdx.y;
    const int z = blockIdx.z;
    const int jbase = blockIdx.x * 64 + wv * 16;
    const short* Qbb = Qb + (size_t)b * TN * DN;

    bf16x8 a0 = *reinterpret_cast<const bf16x8*>(Qbb + (size_t)(jbase + c) * DN + g * 8);
    bf16x8 a1 = *reinterpret_cast<const bf16x8*>(Qbb + (size_t)(jbase + c) * DN + g * 8 + 32);

    const int srow = tid >> 2;
    const int schk = tid & 3;
    const int ilo = z * (TN / 2);

    bf16x8 v0 = *reinterpret_cast<const bf16x8*>(Qbb + (size_t)(ilo + srow) * DN + schk * 16);
    bf16x8 v1 = *reinterpret_cast<const bf16x8*>(Qbb + (size_t)(ilo + srow) * DN + schk * 16 + 8);

    float l[4] = {0.f, 0.f, 0.f, 0.f};
    for (int ii = 0; ii < TN / 2; ii += 64) {
        __syncthreads();
        *reinterpret_cast<bf16x8*>(&Qt[srow * PAD + schk * 16]) = v0;
        *reinterpret_cast<bf16x8*>(&Qt[srow * PAD + schk * 16 + 8]) = v1;
        const int in_ = ilo + ((ii + 64 < TN / 2) ? ii + 64 : ii);
        v0 = *reinterpret_cast<const bf16x8*>(Qbb + (size_t)(in_ + srow) * DN + schk * 16);
        v1 = *reinterpret_cast<const bf16x8*>(Qbb + (size_t)(in_ + srow) * DN + schk * 16 + 8);
        __syncthreads();

        #pragma unroll
        for (int it = 0; it < 4; ++it) {
            bf16x8 b0 = *reinterpret_cast<const bf16x8*>(&Qt[(it * 16 + c) * PAD + g * 8]);
            bf16x8 b1 = *reinterpret_cast<const bf16x8*>(&Qt[(it * 16 + c) * PAD + g * 8 + 32]);
            f32x4 acc = {0.f, 0.f, 0.f, 0.f};
            acc = __builtin_amdgcn_mfma_f32_16x16x32_bf16(a0, b0, acc, 0, 0, 0);
            acc = __builtin_amdgcn_mfma_f32_16x16x32_bf16(a1, b1, acc, 0, 0, 0);
            #pragma unroll
            for (int r = 0; r < 4; ++r)
                l[r] += __expf(acc[r] * 0.125f);
        }
    }
    #pragma unroll
    for (int r = 0; r < 4; ++r) {
        float v = l[r];
        v += __shfl_xor(v, 1);
        v += __shfl_xor(v, 2);
        v += __shfl_xor(v, 4);
        v += __shfl_xor(v, 8);
        l[r] = v;
    }
    if (c == 0) {
        #pragma unroll
        for (int r = 0; r < 4; ++r)
            l_part[((size_t)z * BN + b) * TN + jbase + g * 4 + r] = l[r];
    }
}

// ---------------------------------------------------------------------------
// Kernel F: RT[b][d][j] = QT[b][d][j] / (l_part[0][b][j] + l_part[1][b][j]).
// ---------------------------------------------------------------------------
__global__ __launch_bounds__(256) void fuse_kernel(
    const short* __restrict__ QTb, const float* __restrict__ l_part,
    short* __restrict__ RT)
{
    const int idx = blockIdx.x * 256 + threadIdx.x;
    const int c8 = idx & 255;
    const int bd = idx >> 8;
    const int b = bd >> 6;
    const int j0 = c8 * 8;

    bf16x8 q = *reinterpret_cast<const bf16x8*>(&QTb[(size_t)bd * TN + j0]);
    const float* lp0 = l_part + (size_t)b * TN + j0;
    const float* lp1 = l_part + (size_t)(BN + b) * TN + j0;
    bf16x8 r;
    #pragma unroll
    for (int t = 0; t < 8; ++t)
        r[t] = f2bf(bf2f(q[t]) / (lp0[t] + lp1[t]));
    *reinterpret_cast<bf16x8*>(&RT[(size_t)bd * TN + j0]) = r;
}

// ---------------------------------------------------------------------------
// Kernel C (v7): out_partial[i,:] = sum_{j in z-half} exp(S[i,j]/8) * RT[:,j]
// Grid (TN/64, BN, 2) = 1024 blocks (4/CU). z=0 writes `out0` (= d_out),
// z=1 writes `out1` (ws partial). Plain f32x4 stores — NO atomics (R7's
// mistake: atomicAdd cost 57 MB of write-through). R6 inner loop otherwise.
// ---------------------------------------------------------------------------
__global__ __launch_bounds__(256, 4) void pv_kernel(
    const short* __restrict__ Qb, const short* __restrict__ RT,
    float* __restrict__ out0, float* __restrict__ out1)
{
    __shared__ short Qt[64 * PAD];        // Q[j-local][d]
    __shared__ short RTt[64 * PAD];       // RT[d][j-local]
    __shared__ short Pt[4][16 * PAD];     // per wave: P[i-local][j-local]

    const int tid = threadIdx.x;
    const int lane = tid & 63;
    const int wv = tid >> 6;
    const int c = lane & 15;
    const int g = lane >> 4;
    const int b = blockIdx.y;
    const int z = blockIdx.z;
    const int ibase = blockIdx.x * 64 + wv * 16;
    const short* Qbb = Qb + (size_t)b * TN * DN;
    const short* RTb = RT + (size_t)b * DN * TN;

    bf16x8 bi0 = *reinterpret_cast<const bf16x8*>(Qbb + (size_t)(ibase + c) * DN + g * 8);
    bf16x8 bi1 = *reinterpret_cast<const bf16x8*>(Qbb + (size_t)(ibase + c) * DN + g * 8 + 32);

    f32x4 o[4];
    #pragma unroll
    for (int dt = 0; dt < 4; ++dt) o[dt] = (f32x4){0.f, 0.f, 0.f, 0.f};

    const int srow = tid >> 2;
    const int schk = tid & 3;
    const int jlo = z * (TN / 2);

    bf16x8 vq0 = *reinterpret_cast<const bf16x8*>(Qbb + (size_t)(jlo + srow) * DN + schk * 16);
    bf16x8 vq1 = *reinterpret_cast<const bf16x8*>(Qbb + (size_t)(jlo + srow) * DN + schk * 16 + 8);
    bf16x8 vt0 = *reinterpret_cast<const bf16x8*>(RTb + (size_t)srow * TN + jlo + schk * 16);
    bf16x8 vt1 = *reinterpret_cast<const bf16x8*>(RTb + (size_t)srow * TN + jlo + schk * 16 + 8);

    for (int jj = 0; jj < TN / 2; jj += 64) {
        __syncthreads();
        *reinterpret_cast<bf16x8*>(&Qt[srow * PAD + schk * 16]) = vq0;
        *reinterpret_cast<bf16x8*>(&Qt[srow * PAD + schk * 16 + 8]) = vq1;
        *reinterpret_cast<bf16x8*>(&RTt[srow * PAD + schk * 16]) = vt0;
        *reinterpret_cast<bf16x8*>(&RTt[srow * PAD + schk * 16 + 8]) = vt1;

        const int jn = jlo + ((jj + 64 < TN / 2) ? jj + 64 : jj);
        vq0 = *reinterpret_cast<const bf16x8*>(Qbb + (size_t)(jn + srow) * DN + schk * 16);
        vq1 = *reinterpret_cast<const bf16x8*>(Qbb + (size_t)(jn + srow) * DN + schk * 16 + 8);
        vt0 = *reinterpret_cast<const bf16x8*>(RTb + (size_t)srow * TN + jn + schk * 16);
        vt1 = *reinterpret_cast<const bf16x8*>(RTb + (size_t)srow * TN + jn + schk * 16 + 8);
        __syncthreads();

        // preload phase-B A-frags (RT rows) so the Pt fence doesn't stall them
        bf16x8 aq[4][2];
        #pragma unroll
        for (int dt = 0; dt < 4; ++dt) {
            aq[dt][0] = *reinterpret_cast<const bf16x8*>(&RTt[(dt * 16 + c) * PAD + g * 8]);
            aq[dt][1] = *reinterpret_cast<const bf16x8*>(&RTt[(dt * 16 + c) * PAD + 32 + g * 8]);
        }

        // --- phase A: MFMA1 S^T tiles -> P = exp(s/8) -> Pt (wave-private) ---
        #pragma unroll
        for (int jt = 0; jt < 4; ++jt) {
            bf16x8 a0 = *reinterpret_cast<const bf16x8*>(&Qt[(jt * 16 + c) * PAD + g * 8]);
            bf16x8 a1 = *reinterpret_cast<const bf16x8*>(&Qt[(jt * 16 + c) * PAD + g * 8 + 32]);
            f32x4 accs = {0.f, 0.f, 0.f, 0.f};
            accs = __builtin_amdgcn_mfma_f32_16x16x32_bf16(a0, bi0, accs, 0, 0, 0);
            accs = __builtin_amdgcn_mfma_f32_16x16x32_bf16(a1, bi1, accs, 0, 0, 0);
            bf16x4 pw;
            #pragma unroll
            for (int r = 0; r < 4; ++r)
                pw[r] = f2bf(__expf(accs[r] * 0.125f));
            *reinterpret_cast<bf16x4*>(&Pt[wv][c * PAD + jt * 16 + g * 4]) = pw;
        }
        asm volatile("s_waitcnt lgkmcnt(0)" ::: "memory");
        __builtin_amdgcn_sched_barrier(0);

        // --- phase B: MFMA2 outT[d][i] += RT[d][j] * P[j][i] ---
        bf16x8 p0 = *reinterpret_cast<const bf16x8*>(&Pt[wv][c * PAD + g * 8]);
        bf16x8 p1 = *reinterpret_cast<const bf16x8*>(&Pt[wv][c * PAD + 32 + g * 8]);
        #pragma unroll
        for (int dt = 0; dt < 4; ++dt) {
            o[dt] = __builtin_amdgcn_mfma_f32_16x16x32_bf16(aq[dt][0], p0, o[dt], 0, 0, 0);
            o[dt] = __builtin_amdgcn_mfma_f32_16x16x32_bf16(aq[dt][1], p1, o[dt], 0, 0, 0);
        }
    }

    // epilogue: lane holds outT[dt*16+g*4+r][ibase+c] -> f32x4 stores (no atomics)
    float* outb = (z ? out1 : out0) + (size_t)b * TN * DN;
    #pragma unroll
    for (int dt = 0; dt < 4; ++dt) {
        float4 v4;
        v4.x = o[dt][0]; v4.y = o[dt][1]; v4.z = o[dt][2]; v4.w = o[dt][3];
        *reinterpret_cast<float4*>(&outb[(size_t)(ibase + c) * DN + dt * 16 + g * 4]) = v4;
    }
}

// ---------------------------------------------------------------------------
// Kernel R: out += part1 (float4 grid-stride-free: exact 1 float4/thread).
// ---------------------------------------------------------------------------
__global__ __launch_bounds__(256) void reduce_kernel(
    float* __restrict__ out, const float* __restrict__ part1)
{
    const size_t i = (size_t)blockIdx.x * 256 + threadIdx.x;   // float4 index
    float4 a = reinterpret_cast<float4*>(out)[i];
    float4 b = reinterpret_cast<const float4*>(part1)[i];
    a.x += b.x; a.y += b.y; a.z += b.z; a.w += b.w;
    reinterpret_cast<float4*>(out)[i] = a;
}

extern "C" void kernel_launch(void* const* d_in, const int* in_sizes, int n_in,
                              void* d_out, int out_size, void* d_ws, size_t ws_size,
                              hipStream_t stream) {
    const float* x  = (const float*)d_in[0];
    const float* Wq = (const float*)d_in[1];
    const float* bq = (const float*)d_in[2];
    float* out = (float*)d_out;

    short* Qb   = (short*)d_ws;                           // 4 MB
    short* QTb  = Qb + (size_t)BN * TN * DN;              // 4 MB
    short* RT   = QTb + (size_t)BN * TN * DN;             // 4 MB
    float* lpar = (float*)(RT + (size_t)BN * TN * DN);    // 256 KB
    short* WTh  = (short*)(lpar + (size_t)2 * BN * TN);   // 64 KB
    short* WTl  = WTh + (size_t)DN * EN;                  // 64 KB
    float* part1 = (float*)(WTl + (size_t)DN * EN);       // 8 MB

    wprep_kernel<<<dim3(EN / 64), dim3(256), 0, stream>>>(Wq, WTh, WTl);
    qproj_kernel<<<dim3(BN * TN / 64), dim3(256), 0, stream>>>(x, WTh, WTl, bq, Qb, QTb);
    stats_kernel<<<dim3(TN / 64, BN, 2), dim3(256), 0, stream>>>(Qb, lpar);
    fuse_kernel<<<dim3(BN * DN * TN / 8 / 256), dim3(256), 0, stream>>>(QTb, lpar, RT);
    pv_kernel<<<dim3(TN / 64, BN, 2), dim3(256), 0, stream>>>(Qb, RT, out, part1);
    reduce_kernel<<<dim3(BN * TN * DN / 4 / 256), dim3(256), 0, stream>>>(out, part1);
}

// Round 10
// 79.220 us; speedup vs baseline: 2.5063x; 1.0413x over previous
//
#include <hip/hip_runtime.h>
#include <hip/hip_bf16.h>

#define BN 16
#define TN 2048
#define DN 64
#define EN 512
#define PAD 68   // bf16 row stride 136B: <=2-way (free) banking for our DS patterns

using f32x4  = __attribute__((ext_vector_type(4))) float;
using bf16x8 = __attribute__((ext_vector_type(8))) short;
using bf16x4 = __attribute__((ext_vector_type(4))) short;

static __device__ __forceinline__ short f2bf(float f) {
    __hip_bfloat16 h = __float2bfloat16(f);
    return __builtin_bit_cast(short, h);
}
static __device__ __forceinline__ float bf2f(short s) {
    return __bfloat162float(__builtin_bit_cast(__hip_bfloat16, s));
}

// ---------------------------------------------------------------------------
// Kernel W: split W^T into bf16 hi + lo. Unchanged.
// ---------------------------------------------------------------------------
__global__ __launch_bounds__(256) void wprep_kernel(
    const float* __restrict__ Wq, short* __restrict__ WTh,
    short* __restrict__ WTl)
{
    __shared__ float wlds[64][65];
    const int tid = threadIdx.x;
    const int k0 = blockIdx.x * 64;
    #pragma unroll
    for (int it = 0; it < 16; ++it) {
        int idx = it * 256 + tid;
        int k = idx >> 6, n = idx & 63;
        wlds[k][n] = Wq[(size_t)(k0 + k) * 64 + n];
    }
    __syncthreads();
    #pragma unroll
    for (int it = 0; it < 16; ++it) {
        int idx = it * 256 + tid;
        int n = idx >> 6, k = idx & 63;
        float v = wlds[k][n];
        short h = f2bf(v);
        short l = f2bf(v - bf2f(h));
        WTh[(size_t)n * EN + k0 + k] = h;
        WTl[(size_t)n * EN + k0 + k] = l;
    }
}

// ---------------------------------------------------------------------------
// Kernel A: Q = x @ W + bq via MFMA (bf16 hi+lo W, f32 accum). Unchanged (R6).
// ---------------------------------------------------------------------------
__global__ __launch_bounds__(256, 2) void qproj_kernel(
    const float* __restrict__ x, const short* __restrict__ WTh,
    const short* __restrict__ WTl, const float* __restrict__ bq,
    short* __restrict__ Qb, short* __restrict__ QTb)
{
    __shared__ short xh[64 * 40];
    __shared__ short wth[64 * 40];
    __shared__ short wtl[64 * 40];
    __shared__ short tl[64][68];

    const int tid = threadIdx.x;
    const int lane = tid & 63;
    const int wv = tid >> 6;
    const int c = lane & 15;
    const int g = lane >> 4;
    const int rowbase = blockIdx.x * 64;
    const int b = rowbase >> 11;
    const int tbase = rowbase & (TN - 1);

    const int sr = tid >> 3;
    const int sc4 = tid & 7;

    float4 xa = *reinterpret_cast<const float4*>(&x[(size_t)(rowbase + sr) * EN + sc4 * 4]);
    float4 xb = *reinterpret_cast<const float4*>(&x[(size_t)(rowbase + 32 + sr) * EN + sc4 * 4]);
    bf16x4 wa = *reinterpret_cast<const bf16x4*>(&WTh[(size_t)sr * EN + sc4 * 4]);
    bf16x4 wb = *reinterpret_cast<const bf16x4*>(&WTh[(size_t)(32 + sr) * EN + sc4 * 4]);
    bf16x4 la = *reinterpret_cast<const bf16x4*>(&WTl[(size_t)sr * EN + sc4 * 4]);
    bf16x4 lb = *reinterpret_cast<const bf16x4*>(&WTl[(size_t)(32 + sr) * EN + sc4 * 4]);

    f32x4 acc[4];
    #pragma unroll
    for (int nt = 0; nt < 4; ++nt) acc[nt] = (f32x4){0.f, 0.f, 0.f, 0.f};

    for (int ks = 0; ks < EN; ks += 32) {
        __syncthreads();
        bf16x4 h0, h1;
        #pragma unroll
        for (int j = 0; j < 4; ++j) { h0[j] = f2bf(xa[j]); h1[j] = f2bf(xb[j]); }
        *reinterpret_cast<bf16x4*>(&xh[sr * 40 + sc4 * 4]) = h0;
        *reinterpret_cast<bf16x4*>(&xh[(32 + sr) * 40 + sc4 * 4]) = h1;
        *reinterpret_cast<bf16x4*>(&wth[sr * 40 + sc4 * 4]) = wa;
        *reinterpret_cast<bf16x4*>(&wth[(32 + sr) * 40 + sc4 * 4]) = wb;
        *reinterpret_cast<bf16x4*>(&wtl[sr * 40 + sc4 * 4]) = la;
        *reinterpret_cast<bf16x4*>(&wtl[(32 + sr) * 40 + sc4 * 4]) = lb;

        const int kn = (ks + 32 < EN) ? ks + 32 : ks;
        xa = *reinterpret_cast<const float4*>(&x[(size_t)(rowbase + sr) * EN + kn + sc4 * 4]);
        xb = *reinterpret_cast<const float4*>(&x[(size_t)(rowbase + 32 + sr) * EN + kn + sc4 * 4]);
        wa = *reinterpret_cast<const bf16x4*>(&WTh[(size_t)sr * EN + kn + sc4 * 4]);
        wb = *reinterpret_cast<const bf16x4*>(&WTh[(size_t)(32 + sr) * EN + kn + sc4 * 4]);
        la = *reinterpret_cast<const bf16x4*>(&WTl[(size_t)sr * EN + kn + sc4 * 4]);
        lb = *reinterpret_cast<const bf16x4*>(&WTl[(size_t)(32 + sr) * EN + kn + sc4 * 4]);
        __syncthreads();

        bf16x8 av = *reinterpret_cast<const bf16x8*>(&xh[(wv * 16 + c) * 40 + g * 8]);
        #pragma unroll
        for (int nt = 0; nt < 4; ++nt) {
            bf16x8 bh = *reinterpret_cast<const bf16x8*>(&wth[(nt * 16 + c) * 40 + g * 8]);
            bf16x8 bl = *reinterpret_cast<const bf16x8*>(&wtl[(nt * 16 + c) * 40 + g * 8]);
            acc[nt] = __builtin_amdgcn_mfma_f32_16x16x32_bf16(av, bh, acc[nt], 0, 0, 0);
            acc[nt] = __builtin_amdgcn_mfma_f32_16x16x32_bf16(av, bl, acc[nt], 0, 0, 0);
        }
    }

    __syncthreads();
    #pragma unroll
    for (int nt = 0; nt < 4; ++nt) {
        const float bias = bq[nt * 16 + c];
        #pragma unroll
        for (int r = 0; r < 4; ++r) {
            const int row = wv * 16 + g * 4 + r;
            short qb = f2bf(acc[nt][r] + bias);
            Qb[(size_t)(rowbase + row) * DN + nt * 16 + c] = qb;
            tl[nt * 16 + c][row] = qb;
        }
    }
    __syncthreads();
    #pragma unroll
    for (int it = 0; it < 4; ++it) {
        int idx = it * 256 + tid;
        int d = idx >> 4;
        int j4 = (idx & 15) * 4;
        *reinterpret_cast<short4*>(&QTb[((size_t)(b * 64 + d)) * TN + tbase + j4]) =
            *reinterpret_cast<const short4*>(&tl[d][j4]);
    }
}

// ---------------------------------------------------------------------------
// Kernel B (v8): partial column-softmax sums, z-split 4 (8 iters/block).
// Grid (TN/64, BN, 4) = 2048 blocks; partials to l_part[z][b][t]; no atomics.
// ---------------------------------------------------------------------------
__global__ __launch_bounds__(256, 4) void stats_kernel(
    const short* __restrict__ Qb, float* __restrict__ l_part)
{
    __shared__ short Qt[64 * PAD];
    const int tid = threadIdx.x;
    const int lane = tid & 63;
    const int wv = tid >> 6;
    const int c = lane & 15;
    const int g = lane >> 4;
    const int b = blockIdx.y;
    const int z = blockIdx.z;
    const int jbase = blockIdx.x * 64 + wv * 16;
    const short* Qbb = Qb + (size_t)b * TN * DN;

    bf16x8 a0 = *reinterpret_cast<const bf16x8*>(Qbb + (size_t)(jbase + c) * DN + g * 8);
    bf16x8 a1 = *reinterpret_cast<const bf16x8*>(Qbb + (size_t)(jbase + c) * DN + g * 8 + 32);

    const int srow = tid >> 2;
    const int schk = tid & 3;
    const int ilo = z * (TN / 4);

    bf16x8 v0 = *reinterpret_cast<const bf16x8*>(Qbb + (size_t)(ilo + srow) * DN + schk * 16);
    bf16x8 v1 = *reinterpret_cast<const bf16x8*>(Qbb + (size_t)(ilo + srow) * DN + schk * 16 + 8);

    float l[4] = {0.f, 0.f, 0.f, 0.f};
    for (int ii = 0; ii < TN / 4; ii += 64) {
        __syncthreads();
        *reinterpret_cast<bf16x8*>(&Qt[srow * PAD + schk * 16]) = v0;
        *reinterpret_cast<bf16x8*>(&Qt[srow * PAD + schk * 16 + 8]) = v1;
        const int in_ = ilo + ((ii + 64 < TN / 4) ? ii + 64 : ii);
        v0 = *reinterpret_cast<const bf16x8*>(Qbb + (size_t)(in_ + srow) * DN + schk * 16);
        v1 = *reinterpret_cast<const bf16x8*>(Qbb + (size_t)(in_ + srow) * DN + schk * 16 + 8);
        __syncthreads();

        #pragma unroll
        for (int it = 0; it < 4; ++it) {
            bf16x8 b0 = *reinterpret_cast<const bf16x8*>(&Qt[(it * 16 + c) * PAD + g * 8]);
            bf16x8 b1 = *reinterpret_cast<const bf16x8*>(&Qt[(it * 16 + c) * PAD + g * 8 + 32]);
            f32x4 acc = {0.f, 0.f, 0.f, 0.f};
            acc = __builtin_amdgcn_mfma_f32_16x16x32_bf16(a0, b0, acc, 0, 0, 0);
            acc = __builtin_amdgcn_mfma_f32_16x16x32_bf16(a1, b1, acc, 0, 0, 0);
            #pragma unroll
            for (int r = 0; r < 4; ++r)
                l[r] += __expf(acc[r] * 0.125f);
        }
    }
    #pragma unroll
    for (int r = 0; r < 4; ++r) {
        float v = l[r];
        v += __shfl_xor(v, 1);
        v += __shfl_xor(v, 2);
        v += __shfl_xor(v, 4);
        v += __shfl_xor(v, 8);
        l[r] = v;
    }
    if (c == 0) {
        #pragma unroll
        for (int r = 0; r < 4; ++r)
            l_part[((size_t)z * BN + b) * TN + jbase + g * 4 + r] = l[r];
    }
}

// ---------------------------------------------------------------------------
// Kernel F: RT[b][d][j] = QT[b][d][j] / sum_z l_part[z][b][j]  (4 partials).
// ---------------------------------------------------------------------------
__global__ __launch_bounds__(256) void fuse_kernel(
    const short* __restrict__ QTb, const float* __restrict__ l_part,
    short* __restrict__ RT)
{
    const int idx = blockIdx.x * 256 + threadIdx.x;
    const int c8 = idx & 255;
    const int bd = idx >> 8;
    const int b = bd >> 6;
    const int j0 = c8 * 8;

    bf16x8 q = *reinterpret_cast<const bf16x8*>(&QTb[(size_t)bd * TN + j0]);
    const float* lp0 = l_part + (size_t)b * TN + j0;
    const float* lp1 = l_part + (size_t)(BN + b) * TN + j0;
    const float* lp2 = l_part + (size_t)(2 * BN + b) * TN + j0;
    const float* lp3 = l_part + (size_t)(3 * BN + b) * TN + j0;
    bf16x8 r;
    #pragma unroll
    for (int t = 0; t < 8; ++t)
        r[t] = f2bf(bf2f(q[t]) / (lp0[t] + lp1[t] + lp2[t] + lp3[t]));
    *reinterpret_cast<bf16x8*>(&RT[(size_t)bd * TN + j0]) = r;
}

// ---------------------------------------------------------------------------
// Kernel C (v8): out_partial[i,:] = sum_{j in z-half} exp(S[i,j]/8) * RT[:,j]
// 128-i blocks (4 waves x 32 i) to double arithmetic intensity vs v7: same
// per-iter operand reads (Qt/RTt frags), 2x MFMA. Grid (TN/128, BN, 2) = 512.
// Register-prefetch staging, 2 barriers/iter, wave-private Pt lgkmcnt fence.
// z=0 -> out0 (d_out), z=1 -> out1 (ws); no atomics.
// ---------------------------------------------------------------------------
__global__ __launch_bounds__(256, 2) void pv_kernel(
    const short* __restrict__ Qb, const short* __restrict__ RT,
    float* __restrict__ out0, float* __restrict__ out1)
{
    __shared__ short Qt[64 * PAD];        // Q[j-local][d]          8704 B
    __shared__ short RTt[64 * PAD];       // RT[d][j-local]         8704 B
    __shared__ short Pt[8][16 * PAD];     // per (wave,ih): P tile 17408 B

    const int tid = threadIdx.x;
    const int lane = tid & 63;
    const int wv = tid >> 6;
    const int c = lane & 15;
    const int g = lane >> 4;
    const int b = blockIdx.y;
    const int z = blockIdx.z;
    const int ibase = blockIdx.x * 128 + wv * 32;
    const short* Qbb = Qb + (size_t)b * TN * DN;
    const short* RTb = RT + (size_t)b * DN * TN;

    // invariant MFMA1 B-frags for the wave's two i-halves
    bf16x8 bi[2][2];
    #pragma unroll
    for (int ih = 0; ih < 2; ++ih) {
        const short* p = Qbb + (size_t)(ibase + ih * 16 + c) * DN + g * 8;
        bi[ih][0] = *reinterpret_cast<const bf16x8*>(p);
        bi[ih][1] = *reinterpret_cast<const bf16x8*>(p + 32);
    }

    f32x4 o[4][2];
    #pragma unroll
    for (int dt = 0; dt < 4; ++dt)
        #pragma unroll
        for (int ih = 0; ih < 2; ++ih)
            o[dt][ih] = (f32x4){0.f, 0.f, 0.f, 0.f};

    const int srow = tid >> 2;
    const int schk = tid & 3;
    const int jlo = z * (TN / 2);

    bf16x8 vq0 = *reinterpret_cast<const bf16x8*>(Qbb + (size_t)(jlo + srow) * DN + schk * 16);
    bf16x8 vq1 = *reinterpret_cast<const bf16x8*>(Qbb + (size_t)(jlo + srow) * DN + schk * 16 + 8);
    bf16x8 vt0 = *reinterpret_cast<const bf16x8*>(RTb + (size_t)srow * TN + jlo + schk * 16);
    bf16x8 vt1 = *reinterpret_cast<const bf16x8*>(RTb + (size_t)srow * TN + jlo + schk * 16 + 8);

    for (int jj = 0; jj < TN / 2; jj += 64) {
        __syncthreads();
        *reinterpret_cast<bf16x8*>(&Qt[srow * PAD + schk * 16]) = vq0;
        *reinterpret_cast<bf16x8*>(&Qt[srow * PAD + schk * 16 + 8]) = vq1;
        *reinterpret_cast<bf16x8*>(&RTt[srow * PAD + schk * 16]) = vt0;
        *reinterpret_cast<bf16x8*>(&RTt[srow * PAD + schk * 16 + 8]) = vt1;

        const int jn = jlo + ((jj + 64 < TN / 2) ? jj + 64 : jj);
        vq0 = *reinterpret_cast<const bf16x8*>(Qbb + (size_t)(jn + srow) * DN + schk * 16);
        vq1 = *reinterpret_cast<const bf16x8*>(Qbb + (size_t)(jn + srow) * DN + schk * 16 + 8);
        vt0 = *reinterpret_cast<const bf16x8*>(RTb + (size_t)srow * TN + jn + schk * 16);
        vt1 = *reinterpret_cast<const bf16x8*>(RTb + (size_t)srow * TN + jn + schk * 16 + 8);
        __syncthreads();

        // preload phase-B A-frags (RT rows) so the Pt fence doesn't stall them
        bf16x8 aq[4][2];
        #pragma unroll
        for (int dt = 0; dt < 4; ++dt) {
            aq[dt][0] = *reinterpret_cast<const bf16x8*>(&RTt[(dt * 16 + c) * PAD + g * 8]);
            aq[dt][1] = *reinterpret_cast<const bf16x8*>(&RTt[(dt * 16 + c) * PAD + 32 + g * 8]);
        }

        // --- phase A: MFMA1 S^T tiles -> P = exp(s/8) -> Pt (wave-private) ---
        #pragma unroll
        for (int jt = 0; jt < 4; ++jt) {
            bf16x8 a0 = *reinterpret_cast<const bf16x8*>(&Qt[(jt * 16 + c) * PAD + g * 8]);
            bf16x8 a1 = *reinterpret_cast<const bf16x8*>(&Qt[(jt * 16 + c) * PAD + g * 8 + 32]);
            #pragma unroll
            for (int ih = 0; ih < 2; ++ih) {
                f32x4 accs = {0.f, 0.f, 0.f, 0.f};
                accs = __builtin_amdgcn_mfma_f32_16x16x32_bf16(a0, bi[ih][0], accs, 0, 0, 0);
                accs = __builtin_amdgcn_mfma_f32_16x16x32_bf16(a1, bi[ih][1], accs, 0, 0, 0);
                bf16x4 pw;
                #pragma unroll
                for (int r = 0; r < 4; ++r)
                    pw[r] = f2bf(__expf(accs[r] * 0.125f));
                *reinterpret_cast<bf16x4*>(&Pt[wv * 2 + ih][c * PAD + jt * 16 + g * 4]) = pw;
            }
        }
        asm volatile("s_waitcnt lgkmcnt(0)" ::: "memory");
        __builtin_amdgcn_sched_barrier(0);

        // --- phase B: MFMA2 outT[d][i] += RT[d][j] * P[j][i], both i-halves ---
        #pragma unroll
        for (int ih = 0; ih < 2; ++ih) {
            bf16x8 p0 = *reinterpret_cast<const bf16x8*>(&Pt[wv * 2 + ih][c * PAD + g * 8]);
            bf16x8 p1 = *reinterpret_cast<const bf16x8*>(&Pt[wv * 2 + ih][c * PAD + 32 + g * 8]);
            #pragma unroll
            for (int dt = 0; dt < 4; ++dt) {
                o[dt][ih] = __builtin_amdgcn_mfma_f32_16x16x32_bf16(aq[dt][0], p0, o[dt][ih], 0, 0, 0);
                o[dt][ih] = __builtin_amdgcn_mfma_f32_16x16x32_bf16(aq[dt][1], p1, o[dt][ih], 0, 0, 0);
            }
        }
    }

    // epilogue: lane holds outT[dt*16+g*4+r][ibase+ih*16+c] -> f32x4 stores
    float* outb = (z ? out1 : out0) + (size_t)b * TN * DN;
    #pragma unroll
    for (int dt = 0; dt < 4; ++dt) {
        #pragma unroll
        for (int ih = 0; ih < 2; ++ih) {
            float4 v4;
            v4.x = o[dt][ih][0]; v4.y = o[dt][ih][1];
            v4.z = o[dt][ih][2]; v4.w = o[dt][ih][3];
            *reinterpret_cast<float4*>(
                &outb[(size_t)(ibase + ih * 16 + c) * DN + dt * 16 + g * 4]) = v4;
        }
    }
}

// ---------------------------------------------------------------------------
// Kernel R: out += part1 (exactly 1 float4 per thread).
// ---------------------------------------------------------------------------
__global__ __launch_bounds__(256) void reduce_kernel(
    float* __restrict__ out, const float* __restrict__ part1)
{
    const size_t i = (size_t)blockIdx.x * 256 + threadIdx.x;
    float4 a = reinterpret_cast<float4*>(out)[i];
    float4 b = reinterpret_cast<const float4*>(part1)[i];
    a.x += b.x; a.y += b.y; a.z += b.z; a.w += b.w;
    reinterpret_cast<float4*>(out)[i] = a;
}

extern "C" void kernel_launch(void* const* d_in, const int* in_sizes, int n_in,
                              void* d_out, int out_size, void* d_ws, size_t ws_size,
                              hipStream_t stream) {
    const float* x  = (const float*)d_in[0];
    const float* Wq = (const float*)d_in[1];
    const float* bq = (const float*)d_in[2];
    float* out = (float*)d_out;

    short* Qb   = (short*)d_ws;                           // 4 MB
    short* QTb  = Qb + (size_t)BN * TN * DN;              // 4 MB
    short* RT   = QTb + (size_t)BN * TN * DN;             // 4 MB
    float* lpar = (float*)(RT + (size_t)BN * TN * DN);    // 512 KB (4 partials)
    short* WTh  = (short*)(lpar + (size_t)4 * BN * TN);   // 64 KB
    short* WTl  = WTh + (size_t)DN * EN;                  // 64 KB
    float* part1 = (float*)(WTl + (size_t)DN * EN);       // 8 MB

    wprep_kernel<<<dim3(EN / 64), dim3(256), 0, stream>>>(Wq, WTh, WTl);
    qproj_kernel<<<dim3(BN * TN / 64), dim3(256), 0, stream>>>(x, WTh, WTl, bq, Qb, QTb);
    stats_kernel<<<dim3(TN / 64, BN, 4), dim3(256), 0, stream>>>(Qb, lpar);
    fuse_kernel<<<dim3(BN * DN * TN / 8 / 256), dim3(256), 0, stream>>>(QTb, lpar, RT);
    pv_kernel<<<dim3(TN / 128, BN, 2), dim3(256), 0, stream>>>(Qb, RT, out, part1);
    reduce_kernel<<<dim3(BN * TN * DN / 4 / 256), dim3(256), 0, stream>>>(out, part1);
}

// Round 11
// 78.944 us; speedup vs baseline: 2.5151x; 1.0035x over previous
//
#include <hip/hip_runtime.h>
#include <hip/hip_bf16.h>

#define BN 16
#define TN 2048
#define DN 64
#define EN 512
#define PAD 68   // bf16 row stride 136B

using f32x4  = __attribute__((ext_vector_type(4))) float;
using bf16x8 = __attribute__((ext_vector_type(8))) short;
using bf16x4 = __attribute__((ext_vector_type(4))) short;

static __device__ __forceinline__ short f2bf(float f) {
    __hip_bfloat16 h = __float2bfloat16(f);
    return __builtin_bit_cast(short, h);
}
static __device__ __forceinline__ float bf2f(short s) {
    return __bfloat162float(__builtin_bit_cast(__hip_bfloat16, s));
}
// barrier that makes LDS writes visible but does NOT drain vmcnt:
// in-flight global prefetch loads survive the barrier (T4 pattern).
static __device__ __forceinline__ void bar_lds() {
    asm volatile("s_waitcnt lgkmcnt(0)" ::: "memory");
    __builtin_amdgcn_s_barrier();
}

// ---------------------------------------------------------------------------
// Kernel W: split W^T into bf16 hi + lo. Unchanged.
// ---------------------------------------------------------------------------
__global__ __launch_bounds__(256) void wprep_kernel(
    const float* __restrict__ Wq, short* __restrict__ WTh,
    short* __restrict__ WTl)
{
    __shared__ float wlds[64][65];
    const int tid = threadIdx.x;
    const int k0 = blockIdx.x * 64;
    #pragma unroll
    for (int it = 0; it < 16; ++it) {
        int idx = it * 256 + tid;
        int k = idx >> 6, n = idx & 63;
        wlds[k][n] = Wq[(size_t)(k0 + k) * 64 + n];
    }
    __syncthreads();
    #pragma unroll
    for (int it = 0; it < 16; ++it) {
        int idx = it * 256 + tid;
        int n = idx >> 6, k = idx & 63;
        float v = wlds[k][n];
        short h = f2bf(v);
        short l = f2bf(v - bf2f(h));
        WTh[(size_t)n * EN + k0 + k] = h;
        WTl[(size_t)n * EN + k0 + k] = l;
    }
}

// ---------------------------------------------------------------------------
// Kernel A (v3): Q = x @ W + bq via MFMA (bf16 hi+lo W, f32 accum).
// Double-buffered LDS, ONE lgkm-only barrier per K-step; prefetch loads for
// step t+2 stay in flight across the barrier.
// ---------------------------------------------------------------------------
__global__ __launch_bounds__(256, 2) void qproj_kernel(
    const float* __restrict__ x, const short* __restrict__ WTh,
    const short* __restrict__ WTl, const float* __restrict__ bq,
    short* __restrict__ Qb, short* __restrict__ QTb)
{
    __shared__ short xh[2 * 64 * 40];
    __shared__ short wth[2 * 64 * 40];
    __shared__ short wtl[2 * 64 * 40];
    __shared__ short tl[64][68];

    const int tid = threadIdx.x;
    const int lane = tid & 63;
    const int wv = tid >> 6;
    const int c = lane & 15;
    const int g = lane >> 4;
    const int rowbase = blockIdx.x * 64;
    const int b = rowbase >> 11;
    const int tbase = rowbase & (TN - 1);

    const int sr = tid >> 3;
    const int sc4 = tid & 7;
    const size_t xr0 = (size_t)(rowbase + sr) * EN + sc4 * 4;
    const size_t xr1 = (size_t)(rowbase + 32 + sr) * EN + sc4 * 4;
    const size_t wr0 = (size_t)sr * EN + sc4 * 4;
    const size_t wr1 = (size_t)(32 + sr) * EN + sc4 * 4;

    float4 xa, xb;
    bf16x4 wa, wb, la, lb;

    // prologue: K-step 0 -> buf0; issue K-step 1 loads
    xa = *reinterpret_cast<const float4*>(&x[xr0]);
    xb = *reinterpret_cast<const float4*>(&x[xr1]);
    wa = *reinterpret_cast<const bf16x4*>(&WTh[wr0]);
    wb = *reinterpret_cast<const bf16x4*>(&WTh[wr1]);
    la = *reinterpret_cast<const bf16x4*>(&WTl[wr0]);
    lb = *reinterpret_cast<const bf16x4*>(&WTl[wr1]);
    {
        bf16x4 h0, h1;
        #pragma unroll
        for (int j = 0; j < 4; ++j) { h0[j] = f2bf(xa[j]); h1[j] = f2bf(xb[j]); }
        *reinterpret_cast<bf16x4*>(&xh[sr * 40 + sc4 * 4]) = h0;
        *reinterpret_cast<bf16x4*>(&xh[(32 + sr) * 40 + sc4 * 4]) = h1;
        *reinterpret_cast<bf16x4*>(&wth[sr * 40 + sc4 * 4]) = wa;
        *reinterpret_cast<bf16x4*>(&wth[(32 + sr) * 40 + sc4 * 4]) = wb;
        *reinterpret_cast<bf16x4*>(&wtl[sr * 40 + sc4 * 4]) = la;
        *reinterpret_cast<bf16x4*>(&wtl[(32 + sr) * 40 + sc4 * 4]) = lb;
    }
    xa = *reinterpret_cast<const float4*>(&x[xr0 + 32]);
    xb = *reinterpret_cast<const float4*>(&x[xr1 + 32]);
    wa = *reinterpret_cast<const bf16x4*>(&WTh[wr0 + 32]);
    wb = *reinterpret_cast<const bf16x4*>(&WTh[wr1 + 32]);
    la = *reinterpret_cast<const bf16x4*>(&WTl[wr0 + 32]);
    lb = *reinterpret_cast<const bf16x4*>(&WTl[wr1 + 32]);
    bar_lds();

    f32x4 acc[4];
    #pragma unroll
    for (int nt = 0; nt < 4; ++nt) acc[nt] = (f32x4){0.f, 0.f, 0.f, 0.f};

    for (int t = 0; t < 16; ++t) {
        const int cur = t & 1;
        const int co = cur * 2560;
        if (t + 1 < 16) {
            const int wo = (cur ^ 1) * 2560;
            bf16x4 h0, h1;
            #pragma unroll
            for (int j = 0; j < 4; ++j) { h0[j] = f2bf(xa[j]); h1[j] = f2bf(xb[j]); }
            *reinterpret_cast<bf16x4*>(&xh[wo + sr * 40 + sc4 * 4]) = h0;
            *reinterpret_cast<bf16x4*>(&xh[wo + (32 + sr) * 40 + sc4 * 4]) = h1;
            *reinterpret_cast<bf16x4*>(&wth[wo + sr * 40 + sc4 * 4]) = wa;
            *reinterpret_cast<bf16x4*>(&wth[wo + (32 + sr) * 40 + sc4 * 4]) = wb;
            *reinterpret_cast<bf16x4*>(&wtl[wo + sr * 40 + sc4 * 4]) = la;
            *reinterpret_cast<bf16x4*>(&wtl[wo + (32 + sr) * 40 + sc4 * 4]) = lb;
        }
        if (t + 2 < 16) {
            const int kn = (t + 2) * 32;
            xa = *reinterpret_cast<const float4*>(&x[xr0 + kn]);
            xb = *reinterpret_cast<const float4*>(&x[xr1 + kn]);
            wa = *reinterpret_cast<const bf16x4*>(&WTh[wr0 + kn]);
            wb = *reinterpret_cast<const bf16x4*>(&WTh[wr1 + kn]);
            la = *reinterpret_cast<const bf16x4*>(&WTl[wr0 + kn]);
            lb = *reinterpret_cast<const bf16x4*>(&WTl[wr1 + kn]);
        }

        bf16x8 av = *reinterpret_cast<const bf16x8*>(&xh[co + (wv * 16 + c) * 40 + g * 8]);
        #pragma unroll
        for (int nt = 0; nt < 4; ++nt) {
            bf16x8 bh = *reinterpret_cast<const bf16x8*>(&wth[co + (nt * 16 + c) * 40 + g * 8]);
            bf16x8 bl = *reinterpret_cast<const bf16x8*>(&wtl[co + (nt * 16 + c) * 40 + g * 8]);
            acc[nt] = __builtin_amdgcn_mfma_f32_16x16x32_bf16(av, bh, acc[nt], 0, 0, 0);
            acc[nt] = __builtin_amdgcn_mfma_f32_16x16x32_bf16(av, bl, acc[nt], 0, 0, 0);
        }
        bar_lds();
    }

    __syncthreads();
    #pragma unroll
    for (int nt = 0; nt < 4; ++nt) {
        const float bias = bq[nt * 16 + c];
        #pragma unroll
        for (int r = 0; r < 4; ++r) {
            const int row = wv * 16 + g * 4 + r;
            short qb = f2bf(acc[nt][r] + bias);
            Qb[(size_t)(rowbase + row) * DN + nt * 16 + c] = qb;
            tl[nt * 16 + c][row] = qb;
        }
    }
    __syncthreads();
    #pragma unroll
    for (int it = 0; it < 4; ++it) {
        int idx = it * 256 + tid;
        int d = idx >> 4;
        int j4 = (idx & 15) * 4;
        *reinterpret_cast<short4*>(&QTb[((size_t)(b * 64 + d)) * TN + tbase + j4]) =
            *reinterpret_cast<const short4*>(&tl[d][j4]);
    }
}

// ---------------------------------------------------------------------------
// Kernel B (v9): partial column-softmax sums, z-split 4. Double-buffered Qt,
// one lgkm-only barrier per i-tile; prefetch survives the barrier.
// ---------------------------------------------------------------------------
__global__ __launch_bounds__(256, 4) void stats_kernel(
    const short* __restrict__ Qb, float* __restrict__ l_part)
{
    __shared__ short Qt[2 * 64 * PAD];
    const int tid = threadIdx.x;
    const int lane = tid & 63;
    const int wv = tid >> 6;
    const int c = lane & 15;
    const int g = lane >> 4;
    const int b = blockIdx.y;
    const int z = blockIdx.z;
    const int jbase = blockIdx.x * 64 + wv * 16;
    const short* Qbb = Qb + (size_t)b * TN * DN;

    bf16x8 a0 = *reinterpret_cast<const bf16x8*>(Qbb + (size_t)(jbase + c) * DN + g * 8);
    bf16x8 a1 = *reinterpret_cast<const bf16x8*>(Qbb + (size_t)(jbase + c) * DN + g * 8 + 32);

    const int srow = tid >> 2;
    const int schk = tid & 3;
    const int ilo = z * (TN / 4);
    const int NT = (TN / 4) / 64;            // 8 tiles

    bf16x8 v0, v1;
    v0 = *reinterpret_cast<const bf16x8*>(Qbb + (size_t)(ilo + srow) * DN + schk * 16);
    v1 = *reinterpret_cast<const bf16x8*>(Qbb + (size_t)(ilo + srow) * DN + schk * 16 + 8);
    *reinterpret_cast<bf16x8*>(&Qt[srow * PAD + schk * 16]) = v0;
    *reinterpret_cast<bf16x8*>(&Qt[srow * PAD + schk * 16 + 8]) = v1;
    v0 = *reinterpret_cast<const bf16x8*>(Qbb + (size_t)(ilo + 64 + srow) * DN + schk * 16);
    v1 = *reinterpret_cast<const bf16x8*>(Qbb + (size_t)(ilo + 64 + srow) * DN + schk * 16 + 8);
    bar_lds();

    float l[4] = {0.f, 0.f, 0.f, 0.f};
    for (int t = 0; t < NT; ++t) {
        const int cur = t & 1;
        const int co = cur * 64 * PAD;
        if (t + 1 < NT) {
            const int wo = (cur ^ 1) * 64 * PAD;
            *reinterpret_cast<bf16x8*>(&Qt[wo + srow * PAD + schk * 16]) = v0;
            *reinterpret_cast<bf16x8*>(&Qt[wo + srow * PAD + schk * 16 + 8]) = v1;
        }
        if (t + 2 < NT) {
            const int in_ = ilo + (t + 2) * 64;
            v0 = *reinterpret_cast<const bf16x8*>(Qbb + (size_t)(in_ + srow) * DN + schk * 16);
            v1 = *reinterpret_cast<const bf16x8*>(Qbb + (size_t)(in_ + srow) * DN + schk * 16 + 8);
        }
        #pragma unroll
        for (int it = 0; it < 4; ++it) {
            bf16x8 b0 = *reinterpret_cast<const bf16x8*>(&Qt[co + (it * 16 + c) * PAD + g * 8]);
            bf16x8 b1 = *reinterpret_cast<const bf16x8*>(&Qt[co + (it * 16 + c) * PAD + g * 8 + 32]);
            f32x4 acc = {0.f, 0.f, 0.f, 0.f};
            acc = __builtin_amdgcn_mfma_f32_16x16x32_bf16(a0, b0, acc, 0, 0, 0);
            acc = __builtin_amdgcn_mfma_f32_16x16x32_bf16(a1, b1, acc, 0, 0, 0);
            #pragma unroll
            for (int r = 0; r < 4; ++r)
                l[r] += __expf(acc[r] * 0.125f);
        }
        bar_lds();
    }
    #pragma unroll
    for (int r = 0; r < 4; ++r) {
        float v = l[r];
        v += __shfl_xor(v, 1);
        v += __shfl_xor(v, 2);
        v += __shfl_xor(v, 4);
        v += __shfl_xor(v, 8);
        l[r] = v;
    }
    if (c == 0) {
        #pragma unroll
        for (int r = 0; r < 4; ++r)
            l_part[((size_t)z * BN + b) * TN + jbase + g * 4 + r] = l[r];
    }
}

// ---------------------------------------------------------------------------
// Kernel F: RT[b][d][j] = QT[b][d][j] / sum_z l_part[z][b][j]. Unchanged.
// ---------------------------------------------------------------------------
__global__ __launch_bounds__(256) void fuse_kernel(
    const short* __restrict__ QTb, const float* __restrict__ l_part,
    short* __restrict__ RT)
{
    const int idx = blockIdx.x * 256 + threadIdx.x;
    const int c8 = idx & 255;
    const int bd = idx >> 8;
    const int b = bd >> 6;
    const int j0 = c8 * 8;

    bf16x8 q = *reinterpret_cast<const bf16x8*>(&QTb[(size_t)bd * TN + j0]);
    const float* lp0 = l_part + (size_t)b * TN + j0;
    const float* lp1 = l_part + (size_t)(BN + b) * TN + j0;
    const float* lp2 = l_part + (size_t)(2 * BN + b) * TN + j0;
    const float* lp3 = l_part + (size_t)(3 * BN + b) * TN + j0;
    bf16x8 r;
    #pragma unroll
    for (int t = 0; t < 8; ++t)
        r[t] = f2bf(bf2f(q[t]) / (lp0[t] + lp1[t] + lp2[t] + lp3[t]));
    *reinterpret_cast<bf16x8*>(&RT[(size_t)bd * TN + j0]) = r;
}

// ---------------------------------------------------------------------------
// Kernel C (v9): out_partial[i,:] = sum_{j in z-half} exp(S[i,j]/8) * RT[:,j]
// 128-i blocks (4 waves x 32 i), grid (TN/128, BN, 2) = 512. Double-buffered
// Qt/RTt, ONE lgkm-only barrier per j-tile; tile t+2 loads in flight across
// it. Pt wave-private with lgkmcnt fence. z=0 -> out0, z=1 -> out1.
// ---------------------------------------------------------------------------
__global__ __launch_bounds__(256, 2) void pv_kernel(
    const short* __restrict__ Qb, const short* __restrict__ RT,
    float* __restrict__ out0, float* __restrict__ out1)
{
    __shared__ short Qt[2 * 64 * PAD];    // Q[j-local][d]
    __shared__ short RTt[2 * 64 * PAD];   // RT[d][j-local]
    __shared__ short Pt[8][16 * PAD];     // per (wave,ih): P tile

    const int tid = threadIdx.x;
    const int lane = tid & 63;
    const int wv = tid >> 6;
    const int c = lane & 15;
    const int g = lane >> 4;
    const int b = blockIdx.y;
    const int z = blockIdx.z;
    const int ibase = blockIdx.x * 128 + wv * 32;
    const short* Qbb = Qb + (size_t)b * TN * DN;
    const short* RTb = RT + (size_t)b * DN * TN;

    bf16x8 bi[2][2];
    #pragma unroll
    for (int ih = 0; ih < 2; ++ih) {
        const short* p = Qbb + (size_t)(ibase + ih * 16 + c) * DN + g * 8;
        bi[ih][0] = *reinterpret_cast<const bf16x8*>(p);
        bi[ih][1] = *reinterpret_cast<const bf16x8*>(p + 32);
    }

    f32x4 o[4][2];
    #pragma unroll
    for (int dt = 0; dt < 4; ++dt)
        #pragma unroll
        for (int ih = 0; ih < 2; ++ih)
            o[dt][ih] = (f32x4){0.f, 0.f, 0.f, 0.f};

    const int srow = tid >> 2;
    const int schk = tid & 3;
    const int jlo = z * (TN / 2);
    const int NT = (TN / 2) / 64;            // 16 tiles

    bf16x8 vq0, vq1, vt0, vt1;
    vq0 = *reinterpret_cast<const bf16x8*>(Qbb + (size_t)(jlo + srow) * DN + schk * 16);
    vq1 = *reinterpret_cast<const bf16x8*>(Qbb + (size_t)(jlo + srow) * DN + schk * 16 + 8);
    vt0 = *reinterpret_cast<const bf16x8*>(RTb + (size_t)srow * TN + jlo + schk * 16);
    vt1 = *reinterpret_cast<const bf16x8*>(RTb + (size_t)srow * TN + jlo + schk * 16 + 8);
    *reinterpret_cast<bf16x8*>(&Qt[srow * PAD + schk * 16]) = vq0;
    *reinterpret_cast<bf16x8*>(&Qt[srow * PAD + schk * 16 + 8]) = vq1;
    *reinterpret_cast<bf16x8*>(&RTt[srow * PAD + schk * 16]) = vt0;
    *reinterpret_cast<bf16x8*>(&RTt[srow * PAD + schk * 16 + 8]) = vt1;
    vq0 = *reinterpret_cast<const bf16x8*>(Qbb + (size_t)(jlo + 64 + srow) * DN + schk * 16);
    vq1 = *reinterpret_cast<const bf16x8*>(Qbb + (size_t)(jlo + 64 + srow) * DN + schk * 16 + 8);
    vt0 = *reinterpret_cast<const bf16x8*>(RTb + (size_t)srow * TN + jlo + 64 + schk * 16);
    vt1 = *reinterpret_cast<const bf16x8*>(RTb + (size_t)srow * TN + jlo + 64 + schk * 16 + 8);
    bar_lds();

    for (int t = 0; t < NT; ++t) {
        const int cur = t & 1;
        const int co = cur * 64 * PAD;
        if (t + 1 < NT) {
            const int wo = (cur ^ 1) * 64 * PAD;
            *reinterpret_cast<bf16x8*>(&Qt[wo + srow * PAD + schk * 16]) = vq0;
            *reinterpret_cast<bf16x8*>(&Qt[wo + srow * PAD + schk * 16 + 8]) = vq1;
            *reinterpret_cast<bf16x8*>(&RTt[wo + srow * PAD + schk * 16]) = vt0;
            *reinterpret_cast<bf16x8*>(&RTt[wo + srow * PAD + schk * 16 + 8]) = vt1;
        }
        if (t + 2 < NT) {
            const int jn = jlo + (t + 2) * 64;
            vq0 = *reinterpret_cast<const bf16x8*>(Qbb + (size_t)(jn + srow) * DN + schk * 16);
            vq1 = *reinterpret_cast<const bf16x8*>(Qbb + (size_t)(jn + srow) * DN + schk * 16 + 8);
            vt0 = *reinterpret_cast<const bf16x8*>(RTb + (size_t)srow * TN + jn + schk * 16);
            vt1 = *reinterpret_cast<const bf16x8*>(RTb + (size_t)srow * TN + jn + schk * 16 + 8);
        }

        // preload phase-B A-frags (RT rows)
        bf16x8 aq[4][2];
        #pragma unroll
        for (int dt = 0; dt < 4; ++dt) {
            aq[dt][0] = *reinterpret_cast<const bf16x8*>(&RTt[co + (dt * 16 + c) * PAD + g * 8]);
            aq[dt][1] = *reinterpret_cast<const bf16x8*>(&RTt[co + (dt * 16 + c) * PAD + 32 + g * 8]);
        }

        // --- phase A: MFMA1 S^T tiles -> P = exp(s/8) -> Pt (wave-private) ---
        #pragma unroll
        for (int jt = 0; jt < 4; ++jt) {
            bf16x8 a0 = *reinterpret_cast<const bf16x8*>(&Qt[co + (jt * 16 + c) * PAD + g * 8]);
            bf16x8 a1 = *reinterpret_cast<const bf16x8*>(&Qt[co + (jt * 16 + c) * PAD + g * 8 + 32]);
            #pragma unroll
            for (int ih = 0; ih < 2; ++ih) {
                f32x4 accs = {0.f, 0.f, 0.f, 0.f};
                accs = __builtin_amdgcn_mfma_f32_16x16x32_bf16(a0, bi[ih][0], accs, 0, 0, 0);
                accs = __builtin_amdgcn_mfma_f32_16x16x32_bf16(a1, bi[ih][1], accs, 0, 0, 0);
                bf16x4 pw;
                #pragma unroll
                for (int r = 0; r < 4; ++r)
                    pw[r] = f2bf(__expf(accs[r] * 0.125f));
                *reinterpret_cast<bf16x4*>(&Pt[wv * 2 + ih][c * PAD + jt * 16 + g * 4]) = pw;
            }
        }
        asm volatile("s_waitcnt lgkmcnt(0)" ::: "memory");
        __builtin_amdgcn_sched_barrier(0);

        // --- phase B: MFMA2 outT[d][i] += RT[d][j] * P[j][i], both i-halves ---
        #pragma unroll
        for (int ih = 0; ih < 2; ++ih) {
            bf16x8 p0 = *reinterpret_cast<const bf16x8*>(&Pt[wv * 2 + ih][c * PAD + g * 8]);
            bf16x8 p1 = *reinterpret_cast<const bf16x8*>(&Pt[wv * 2 + ih][c * PAD + 32 + g * 8]);
            #pragma unroll
            for (int dt = 0; dt < 4; ++dt) {
                o[dt][ih] = __builtin_amdgcn_mfma_f32_16x16x32_bf16(aq[dt][0], p0, o[dt][ih], 0, 0, 0);
                o[dt][ih] = __builtin_amdgcn_mfma_f32_16x16x32_bf16(aq[dt][1], p1, o[dt][ih], 0, 0, 0);
            }
        }
        bar_lds();
    }

    // epilogue: lane holds outT[dt*16+g*4+r][ibase+ih*16+c] -> f32x4 stores
    float* outb = (z ? out1 : out0) + (size_t)b * TN * DN;
    #pragma unroll
    for (int dt = 0; dt < 4; ++dt) {
        #pragma unroll
        for (int ih = 0; ih < 2; ++ih) {
            float4 v4;
            v4.x = o[dt][ih][0]; v4.y = o[dt][ih][1];
            v4.z = o[dt][ih][2]; v4.w = o[dt][ih][3];
            *reinterpret_cast<float4*>(
                &outb[(size_t)(ibase + ih * 16 + c) * DN + dt * 16 + g * 4]) = v4;
        }
    }
}

// ---------------------------------------------------------------------------
// Kernel R: out += part1 (exactly 1 float4 per thread).
// ---------------------------------------------------------------------------
__global__ __launch_bounds__(256) void reduce_kernel(
    float* __restrict__ out, const float* __restrict__ part1)
{
    const size_t i = (size_t)blockIdx.x * 256 + threadIdx.x;
    float4 a = reinterpret_cast<float4*>(out)[i];
    float4 b = reinterpret_cast<const float4*>(part1)[i];
    a.x += b.x; a.y += b.y; a.z += b.z; a.w += b.w;
    reinterpret_cast<float4*>(out)[i] = a;
}

extern "C" void kernel_launch(void* const* d_in, const int* in_sizes, int n_in,
                              void* d_out, int out_size, void* d_ws, size_t ws_size,
                              hipStream_t stream) {
    const float* x  = (const float*)d_in[0];
    const float* Wq = (const float*)d_in[1];
    const float* bq = (const float*)d_in[2];
    float* out = (float*)d_out;

    short* Qb   = (short*)d_ws;                           // 4 MB
    short* QTb  = Qb + (size_t)BN * TN * DN;              // 4 MB
    short* RT   = QTb + (size_t)BN * TN * DN;             // 4 MB
    float* lpar = (float*)(RT + (size_t)BN * TN * DN);    // 512 KB
    short* WTh  = (short*)(lpar + (size_t)4 * BN * TN);   // 64 KB
    short* WTl  = WTh + (size_t)DN * EN;                  // 64 KB
    float* part1 = (float*)(WTl + (size_t)DN * EN);       // 8 MB

    wprep_kernel<<<dim3(EN / 64), dim3(256), 0, stream>>>(Wq, WTh, WTl);
    qproj_kernel<<<dim3(BN * TN / 64), dim3(256), 0, stream>>>(x, WTh, WTl, bq, Qb, QTb);
    stats_kernel<<<dim3(TN / 64, BN, 4), dim3(256), 0, stream>>>(Qb, lpar);
    fuse_kernel<<<dim3(BN * DN * TN / 8 / 256), dim3(256), 0, stream>>>(QTb, lpar, RT);
    pv_kernel<<<dim3(TN / 128, BN, 2), dim3(256), 0, stream>>>(Qb, RT, out, part1);
    reduce_kernel<<<dim3(BN * TN * DN / 4 / 256), dim3(256), 0, stream>>>(out, part1);
}